// Round 1
// baseline (9092.164 us; speedup 1.0000x reference)
//
#include <hip/hip_runtime.h>
#include <hip/hip_bf16.h>

// Problem dims (fixed)
#define B_ 32
#define S_ 64
#define H_ 512
#define T_ 32
#define V_ 32000

typedef __attribute__((ext_vector_type(8))) short bf16x8;
typedef __attribute__((ext_vector_type(4))) float f32x4;

static __device__ __forceinline__ unsigned short f2bf(float f) {
    unsigned int u = __float_as_uint(f);
    u += 0x7FFF + ((u >> 16) & 1);   // RNE
    return (unsigned short)(u >> 16);
}

// ---------------------------------------------------------------------------
// C[m,n] = sum_k A[m,k] * B[n,k] + bias[n]      (B stored N-major x K, "B^T")
// A: fp32 or bf16 (template), row-major M x K.  M % 128 == 0, N % 128 == 0,
// K % 32 == 0.  Tile 128x128, BK=32, 4 waves, each wave 4x4 frags of 16x16x32.
// ---------------------------------------------------------------------------
template <bool A_BF16>
__global__ __launch_bounds__(256, 2)
void gemm_bt(const void* __restrict__ Av, const float* __restrict__ Bm,
             const float* __restrict__ bias, float* __restrict__ C,
             int M, int N, int K)
{
    __shared__ unsigned short As[128 * 32];
    __shared__ unsigned short Bs[128 * 32];

    const int m0 = blockIdx.x * 128;
    const int n0 = blockIdx.y * 128;
    const int tid  = threadIdx.x;
    const int lane = tid & 63;
    const int wave = tid >> 6;
    const int wm   = (wave & 1) * 64;
    const int wn   = (wave >> 1) * 64;
    const int quad = lane >> 4;   // 0..3
    const int l16  = lane & 15;

    f32x4 acc[4][4];
#pragma unroll
    for (int i = 0; i < 4; i++)
#pragma unroll
        for (int j = 0; j < 4; j++) acc[i][j] = (f32x4){0.f, 0.f, 0.f, 0.f};

    const int r0 = tid >> 2;  // 0..63 (row group)
    const int q4 = tid & 3;   // 0..3  (k sub-chunk of 8)

    for (int k0 = 0; k0 < K; k0 += 32) {
        __syncthreads();  // protect LDS from previous iteration's readers
#pragma unroll
        for (int rr = 0; rr < 2; rr++) {
            const int row = r0 + rr * 64;
            // --- stage A tile (128 x 32) as bf16 ---
            if (A_BF16) {
                const unsigned short* A16 = (const unsigned short*)Av;
                const uint4 v = *(const uint4*)(A16 + (size_t)(m0 + row) * K + k0 + q4 * 8);
                *(uint4*)(&As[row * 32 + q4 * 8]) = v;
            } else {
                const float* A32 = (const float*)Av;
                const float4 s0 = *(const float4*)(A32 + (size_t)(m0 + row) * K + k0 + q4 * 8);
                const float4 s1 = *(const float4*)(A32 + (size_t)(m0 + row) * K + k0 + q4 * 8 + 4);
                unsigned short tmp[8] = {f2bf(s0.x), f2bf(s0.y), f2bf(s0.z), f2bf(s0.w),
                                         f2bf(s1.x), f2bf(s1.y), f2bf(s1.z), f2bf(s1.w)};
                *(uint4*)(&As[row * 32 + q4 * 8]) = *(uint4*)tmp;
            }
            // --- stage B tile (128 x 32) fp32 -> bf16 ---
            const float4 t0 = *(const float4*)(Bm + (size_t)(n0 + row) * K + k0 + q4 * 8);
            const float4 t1 = *(const float4*)(Bm + (size_t)(n0 + row) * K + k0 + q4 * 8 + 4);
            unsigned short tb[8] = {f2bf(t0.x), f2bf(t0.y), f2bf(t0.z), f2bf(t0.w),
                                    f2bf(t1.x), f2bf(t1.y), f2bf(t1.z), f2bf(t1.w)};
            *(uint4*)(&Bs[row * 32 + q4 * 8]) = *(uint4*)tb;
        }
        __syncthreads();

        // fragments: A[m=lane&15][k=quad*8+j], B[n=lane&15][k=quad*8+j]
        bf16x8 af[4], bfr[4];
#pragma unroll
        for (int i = 0; i < 4; i++)
            af[i] = *(const bf16x8*)(&As[(wm + 16 * i + l16) * 32 + quad * 8]);
#pragma unroll
        for (int j = 0; j < 4; j++)
            bfr[j] = *(const bf16x8*)(&Bs[(wn + 16 * j + l16) * 32 + quad * 8]);
#pragma unroll
        for (int i = 0; i < 4; i++)
#pragma unroll
            for (int j = 0; j < 4; j++)
                acc[i][j] = __builtin_amdgcn_mfma_f32_16x16x32_bf16(af[i], bfr[j], acc[i][j], 0, 0, 0);
    }

    // epilogue: C/D layout col = lane&15, row = quad*4 + reg
#pragma unroll
    for (int i = 0; i < 4; i++)
#pragma unroll
        for (int j = 0; j < 4; j++)
#pragma unroll
            for (int r = 0; r < 4; r++) {
                const int m = m0 + wm + 16 * i + quad * 4 + r;
                const int n = n0 + wn + 16 * j + l16;
                C[(size_t)m * N + n] = acc[i][j][r] + bias[n];
            }
}

// ---------------------------------------------------------------------------
// h0[b,j] = sum_k ehid[b,k] * Wh[j,k] + bh[j]   (B x H outputs, K=1024)
// ---------------------------------------------------------------------------
__global__ void k_h0(const float* __restrict__ ehid, const float* __restrict__ Wh,
                     const float* __restrict__ bh, float* __restrict__ h)
{
    const int o = blockIdx.x * 256 + threadIdx.x;  // 16384
    const int b = o >> 9, j = o & 511;
    const float* x = ehid + b * 1024;
    const float* w = Wh + (size_t)j * 1024;
    float s = 0.f;
    for (int k = 0; k < 1024; k += 4) {
        float4 xv = *(const float4*)(x + k);
        float4 wv = *(const float4*)(w + k);
        s += xv.x * wv.x + xv.y * wv.y + xv.z * wv.z + xv.w * wv.w;
    }
    h[o] = s + bh[j];
}

// ---------------------------------------------------------------------------
// q[b,j]  = sum_k h[b,k]*Wa_w[j,k]   + Wa_b[j]        (j < 512)
// gh[b,j] = sum_k h[b,k]*W_hh[j,k]   + b_hh[j]        (j < 1536)
// one thread per output; 32 b * 2048 j = 65536 threads
// ---------------------------------------------------------------------------
__global__ void k_qgh(const float* __restrict__ h, const float* __restrict__ Wa_w,
                      const float* __restrict__ Wa_b, const float* __restrict__ W_hh,
                      const float* __restrict__ b_hh, float* __restrict__ q,
                      float* __restrict__ gh)
{
    const int o = blockIdx.x * 256 + threadIdx.x;
    const int b = o >> 11, jg = o & 2047;
    const float* hb = h + b * 512;
    const float* w;
    if (jg < 512) w = Wa_w + (size_t)jg * 512;
    else          w = W_hh + (size_t)(jg - 512) * 512;
    float s = 0.f;
    for (int k = 0; k < 512; k += 4) {
        float4 xv = *(const float4*)(hb + k);
        float4 wv = *(const float4*)(w + k);
        s += xv.x * wv.x + xv.y * wv.y + xv.z * wv.z + xv.w * wv.w;
    }
    if (jg < 512) q[b * 512 + jg] = s + Wa_b[jg];
    else          gh[b * 1536 + (jg - 512)] = s + b_hh[jg - 512];
}

// ---------------------------------------------------------------------------
// Attention for one decode step. One block per batch element b.
// scores[s] = Va . tanh(q[b] + ua[b,s]) + Va_b ; w = softmax(scores)
// ctx[b,m] = sum_s w[s] * enc[b,s,m] ; also writes attn output.
// ---------------------------------------------------------------------------
__global__ void k_attn(const float* __restrict__ q, const float* __restrict__ ua,
                       const float* __restrict__ Va_w, const float* __restrict__ Va_b,
                       const float* __restrict__ enc, float* __restrict__ ctx,
                       float* __restrict__ attn_out, int t)
{
    __shared__ float qs[512];
    __shared__ float parts[64][4];
    __shared__ float wsm[64];
    const int b = blockIdx.x;
    const int tid = threadIdx.x;

    for (int i = tid; i < 512; i += 256) qs[i] = q[b * 512 + i];
    __syncthreads();

    const int s = tid >> 2, p = tid & 3;
    {
        const float* uar = ua + ((size_t)(b * 64 + s)) * 512 + p * 128;
        const float* qp = qs + p * 128;
        const float* vp = Va_w + p * 128;
        float acc = 0.f;
        for (int k = 0; k < 128; k++) acc += vp[k] * tanhf(qp[k] + uar[k]);
        parts[s][p] = acc;
    }
    __syncthreads();

    if (tid < 64) {
        float sc = parts[tid][0] + parts[tid][1] + parts[tid][2] + parts[tid][3] + Va_b[0];
        float mx = sc;
        for (int off = 32; off; off >>= 1) mx = fmaxf(mx, __shfl_down(mx, off));
        mx = __shfl(mx, 0);
        float e = expf(sc - mx);
        float sum = e;
        for (int off = 32; off; off >>= 1) sum += __shfl_down(sum, off);
        sum = __shfl(sum, 0);
        float w = e / sum;
        wsm[tid] = w;
        attn_out[((size_t)b * T_ + t) * 64 + tid] = w;
    }
    __syncthreads();

    for (int mm = tid; mm < 1024; mm += 256) {
        float a = 0.f;
        for (int s2 = 0; s2 < 64; s2++)
            a += wsm[s2] * enc[((size_t)(b * 64 + s2)) * 1024 + mm];
        ctx[b * 1024 + mm] = a;
    }
}

// ---------------------------------------------------------------------------
// Fused GRU cell: gx = [emb[tok], ctx] @ W_ih.T + b_ih ; gates; h update.
// One thread per (b, j). Writes fp32 h in-place, bf16 row into Hall, and
// optionally h_final. gh already contains b_hh.
// ---------------------------------------------------------------------------
__global__ void k_gru(const float* __restrict__ emb, const int* __restrict__ tgt,
                      const float* __restrict__ ctx, const float* __restrict__ W_ih,
                      const float* __restrict__ b_ih, const float* __restrict__ gh,
                      float* __restrict__ h, unsigned short* __restrict__ Hall,
                      float* __restrict__ hfin, int t)
{
    const int o = blockIdx.x * 256 + threadIdx.x;  // 16384
    const int b = o >> 9, j = o & 511;
    const int tok = (t == 0) ? 0 : tgt[b * T_ + (t - 1)];
    const float* xe = emb + (size_t)tok * 512;
    const float* xc = ctx + b * 1024;
    const float* wr = W_ih + (size_t)j * 1536;
    const float* wz = W_ih + (size_t)(512 + j) * 1536;
    const float* wn = W_ih + (size_t)(1024 + j) * 1536;

    float sr = 0.f, sz = 0.f, sn = 0.f;
    for (int k = 0; k < 512; k += 4) {
        float4 xv = *(const float4*)(xe + k);
        float4 r4 = *(const float4*)(wr + k);
        float4 z4 = *(const float4*)(wz + k);
        float4 n4 = *(const float4*)(wn + k);
        sr += xv.x * r4.x + xv.y * r4.y + xv.z * r4.z + xv.w * r4.w;
        sz += xv.x * z4.x + xv.y * z4.y + xv.z * z4.z + xv.w * z4.w;
        sn += xv.x * n4.x + xv.y * n4.y + xv.z * n4.z + xv.w * n4.w;
    }
    for (int k = 0; k < 1024; k += 4) {
        float4 xv = *(const float4*)(xc + k);
        float4 r4 = *(const float4*)(wr + 512 + k);
        float4 z4 = *(const float4*)(wz + 512 + k);
        float4 n4 = *(const float4*)(wn + 512 + k);
        sr += xv.x * r4.x + xv.y * r4.y + xv.z * r4.z + xv.w * r4.w;
        sz += xv.x * z4.x + xv.y * z4.y + xv.z * z4.z + xv.w * z4.w;
        sn += xv.x * n4.x + xv.y * n4.y + xv.z * n4.z + xv.w * n4.w;
    }
    const float ghr = gh[b * 1536 + j];
    const float ghz = gh[b * 1536 + 512 + j];
    const float ghn = gh[b * 1536 + 1024 + j];
    const float gxr = sr + b_ih[j];
    const float gxz = sz + b_ih[512 + j];
    const float gxn = sn + b_ih[1024 + j];
    const float r = 1.f / (1.f + expf(-(gxr + ghr)));
    const float z = 1.f / (1.f + expf(-(gxz + ghz)));
    const float n = tanhf(gxn + r * ghn);
    const float hn = (1.f - z) * n + z * h[o];
    h[o] = hn;
    Hall[((size_t)b * T_ + t) * 512 + j] = f2bf(hn);
    if (hfin) hfin[o] = hn;
}

// ---------------------------------------------------------------------------
// In-place log_softmax over V=32000 per row. One block (256 thr) per row.
// ---------------------------------------------------------------------------
__global__ void k_logsoftmax(float* __restrict__ logits)
{
    __shared__ float red[4];
    __shared__ float red2[4];
    const int row = blockIdx.x;
    float* p = logits + (size_t)row * V_;
    const int tid = threadIdx.x;

    float mx = -1e30f;
    for (int i = tid; i < V_; i += 256) mx = fmaxf(mx, p[i]);
    for (int off = 32; off; off >>= 1) mx = fmaxf(mx, __shfl_down(mx, off));
    if ((tid & 63) == 0) red[tid >> 6] = mx;
    __syncthreads();
    mx = fmaxf(fmaxf(red[0], red[1]), fmaxf(red[2], red[3]));

    float sum = 0.f;
    for (int i = tid; i < V_; i += 256) sum += expf(p[i] - mx);
    for (int off = 32; off; off >>= 1) sum += __shfl_down(sum, off);
    if ((tid & 63) == 0) red2[tid >> 6] = sum;
    __syncthreads();
    sum = red2[0] + red2[1] + red2[2] + red2[3];

    const float lse = mx + logf(sum);
    for (int i = tid; i < V_; i += 256) p[i] = p[i] - lse;
}

// ---------------------------------------------------------------------------
extern "C" void kernel_launch(void* const* d_in, const int* in_sizes, int n_in,
                              void* d_out, int out_size, void* d_ws, size_t ws_size,
                              hipStream_t stream)
{
    const float* enc   = (const float*)d_in[0];   // [B,S,2H]
    const float* ehid  = (const float*)d_in[1];   // [1,B,2H]
    const int*   tgt   = (const int*)d_in[2];     // [B,T]
    const float* emb   = (const float*)d_in[3];   // [V,H]
    const float* Wa_w  = (const float*)d_in[4];   // [H,H]
    const float* Wa_b  = (const float*)d_in[5];
    const float* Ua_w  = (const float*)d_in[6];   // [H,2H]
    const float* Ua_b  = (const float*)d_in[7];
    const float* Va_w  = (const float*)d_in[8];   // [1,H]
    const float* Va_b  = (const float*)d_in[9];   // [1]
    const float* W_ih  = (const float*)d_in[10];  // [3H,3H]
    const float* b_ih  = (const float*)d_in[11];
    const float* W_hh  = (const float*)d_in[12];  // [3H,H]
    const float* b_hh  = (const float*)d_in[13];
    const float* Wh    = (const float*)d_in[14];  // [H,2H]
    const float* bh    = (const float*)d_in[15];
    const float* out_w = (const float*)d_in[16];  // [V,H]
    const float* out_b = (const float*)d_in[17];  // [V]

    float* outp = (float*)d_out;
    float* lp   = outp;                       // [B,T,V] = 32,768,000 floats
    float* hf   = outp + 32768000;            // [1,B,H] = 16,384
    float* attn = outp + 32784384;            // [B,T,S] = 65,536

    // workspace layout (floats); total ~5.7 MB
    float* ws  = (float*)d_ws;
    float* h   = ws;                // 16384
    float* q   = ws + 16384;        // 16384
    float* gh  = ws + 32768;        // 49152
    float* ctx = ws + 81920;        // 32768
    float* ua  = ws + 114688;       // 1,048,576 ([B*S, H])
    unsigned short* Hall = (unsigned short*)(ws + 1163264);  // [B*T, H] bf16

    // setup: h0 and ua_keys (independent)
    k_h0<<<64, 256, 0, stream>>>(ehid, Wh, bh, h);
    gemm_bt<false><<<dim3(16, 4), 256, 0, stream>>>(enc, Ua_w, Ua_b, ua,
                                                    2048, 512, 1024);

    // sequential scan over T steps
    for (int t = 0; t < T_; t++) {
        k_qgh<<<256, 256, 0, stream>>>(h, Wa_w, Wa_b, W_hh, b_hh, q, gh);
        k_attn<<<32, 256, 0, stream>>>(q, ua, Va_w, Va_b, enc, ctx, attn, t);
        k_gru<<<64, 256, 0, stream>>>(emb, tgt, ctx, W_ih, b_ih, gh, h, Hall,
                                      (t == T_ - 1) ? hf : nullptr, t);
    }

    // batched logits GEMM: [1024, 512] x [32000, 512]^T -> d_out
    gemm_bt<true><<<dim3(8, 250), 256, 0, stream>>>(Hall, out_w, out_b, lp,
                                                    1024, V_, 512);
    // in-place log_softmax
    k_logsoftmax<<<1024, 256, 0, stream>>>(lp);
}

// Round 2
// 2023.404 us; speedup vs baseline: 4.4935x; 4.4935x over previous
//
#include <hip/hip_runtime.h>
#include <hip/hip_bf16.h>

// Problem dims (fixed)
#define B_ 32
#define S_ 64
#define H_ 512
#define T_ 32
#define V_ 32000

typedef __attribute__((ext_vector_type(8))) short bf16x8;
typedef __attribute__((ext_vector_type(4))) float f32x4;

static __device__ __forceinline__ unsigned short f2bf(float f) {
    unsigned int u = __float_as_uint(f);
    u += 0x7FFF + ((u >> 16) & 1);   // RNE
    return (unsigned short)(u >> 16);
}
static __device__ __forceinline__ float dot4(float4 a, float4 b) {
    return a.x * b.x + a.y * b.y + a.z * b.z + a.w * b.w;
}
static __device__ __forceinline__ float tanh_fast(float x) {
    x = fminf(fmaxf(x, -15.f), 15.f);
    float e = __expf(2.f * x);
    return (e - 1.f) / (e + 1.f);
}
static __device__ __forceinline__ float sigmoid_fast(float x) {
    return 1.f / (1.f + __expf(-x));
}

// ---------------------------------------------------------------------------
// C[m,n] = sum_k A[m,k] * B[n,k] + bias[n]   (B rows have leading dim Bld)
// A: fp32 or bf16, row-major M x K. M%128==0, N%128==0, K%32==0.
// Tile 128x128, BK=32, 4 waves, each wave 4x4 frags of 16x16x32 bf16 MFMA.
// ---------------------------------------------------------------------------
template <bool A_BF16>
__global__ __launch_bounds__(256, 2)
void gemm_bt(const void* __restrict__ Av, const float* __restrict__ Bm,
             const float* __restrict__ bias, float* __restrict__ C,
             int M, int N, int K, int Bld)
{
    __shared__ unsigned short As[128 * 32];
    __shared__ unsigned short Bs[128 * 32];

    const int m0 = blockIdx.x * 128;
    const int n0 = blockIdx.y * 128;
    const int tid  = threadIdx.x;
    const int lane = tid & 63;
    const int wave = tid >> 6;
    const int wm   = (wave & 1) * 64;
    const int wn   = (wave >> 1) * 64;
    const int quad = lane >> 4;   // 0..3
    const int l16  = lane & 15;

    f32x4 acc[4][4];
#pragma unroll
    for (int i = 0; i < 4; i++)
#pragma unroll
        for (int j = 0; j < 4; j++) acc[i][j] = (f32x4){0.f, 0.f, 0.f, 0.f};

    const int r0 = tid >> 2;  // 0..63 (row group)
    const int q4 = tid & 3;   // 0..3  (k sub-chunk of 8)

    for (int k0 = 0; k0 < K; k0 += 32) {
        __syncthreads();
#pragma unroll
        for (int rr = 0; rr < 2; rr++) {
            const int row = r0 + rr * 64;
            if (A_BF16) {
                const unsigned short* A16 = (const unsigned short*)Av;
                const uint4 v = *(const uint4*)(A16 + (size_t)(m0 + row) * K + k0 + q4 * 8);
                *(uint4*)(&As[row * 32 + q4 * 8]) = v;
            } else {
                const float* A32 = (const float*)Av;
                const float4 s0 = *(const float4*)(A32 + (size_t)(m0 + row) * K + k0 + q4 * 8);
                const float4 s1 = *(const float4*)(A32 + (size_t)(m0 + row) * K + k0 + q4 * 8 + 4);
                unsigned short tmp[8] = {f2bf(s0.x), f2bf(s0.y), f2bf(s0.z), f2bf(s0.w),
                                         f2bf(s1.x), f2bf(s1.y), f2bf(s1.z), f2bf(s1.w)};
                *(uint4*)(&As[row * 32 + q4 * 8]) = *(uint4*)tmp;
            }
            const float4 t0 = *(const float4*)(Bm + (size_t)(n0 + row) * Bld + k0 + q4 * 8);
            const float4 t1 = *(const float4*)(Bm + (size_t)(n0 + row) * Bld + k0 + q4 * 8 + 4);
            unsigned short tb[8] = {f2bf(t0.x), f2bf(t0.y), f2bf(t0.z), f2bf(t0.w),
                                    f2bf(t1.x), f2bf(t1.y), f2bf(t1.z), f2bf(t1.w)};
            *(uint4*)(&Bs[row * 32 + q4 * 8]) = *(uint4*)tb;
        }
        __syncthreads();

        bf16x8 af[4], bfr[4];
#pragma unroll
        for (int i = 0; i < 4; i++)
            af[i] = *(const bf16x8*)(&As[(wm + 16 * i + l16) * 32 + quad * 8]);
#pragma unroll
        for (int j = 0; j < 4; j++)
            bfr[j] = *(const bf16x8*)(&Bs[(wn + 16 * j + l16) * 32 + quad * 8]);
#pragma unroll
        for (int i = 0; i < 4; i++)
#pragma unroll
            for (int j = 0; j < 4; j++)
                acc[i][j] = __builtin_amdgcn_mfma_f32_16x16x32_bf16(af[i], bfr[j], acc[i][j], 0, 0, 0);
    }

#pragma unroll
    for (int i = 0; i < 4; i++)
#pragma unroll
        for (int j = 0; j < 4; j++)
#pragma unroll
            for (int r = 0; r < 4; r++) {
                const int m = m0 + wm + 16 * i + quad * 4 + r;
                const int n = n0 + wn + 16 * j + l16;
                C[(size_t)m * N + n] = acc[i][j][r] + bias[n];
            }
}

// ---------------------------------------------------------------------------
// h0 split-K partials: thread = (b, j, c) c in 0..3, K-chunk 256 of K=1024.
// ---------------------------------------------------------------------------
__global__ void k_h0part(const float* __restrict__ ehid, const float* __restrict__ Wh,
                         float* __restrict__ h0p)
{
    const int o = blockIdx.x * 256 + threadIdx.x;  // 65536
    const int b = o & 31, j = (o >> 5) & 511, c = o >> 14;
    const float* x = ehid + b * 1024 + c * 256;
    const float* w = Wh + (size_t)j * 1024 + c * 256;
    float s = 0.f;
#pragma unroll 8
    for (int k = 0; k < 256; k += 4)
        s += dot4(*(const float4*)(x + k), *(const float4*)(w + k));
    h0p[c * 16384 + b * 512 + j] = s;
}

__global__ void k_h0fin(const float* __restrict__ h0p, const float* __restrict__ bh,
                        float* __restrict__ h)
{
    const int o = blockIdx.x * 256 + threadIdx.x;  // 16384
    h[o] = bh[o & 511] + h0p[o] + h0p[16384 + o] + h0p[32768 + o] + h0p[49152 + o];
}

// ---------------------------------------------------------------------------
// Gather teacher-forced embedding rows: Xemb[b*T+t, :] = emb[tok(b,t), :]
// ---------------------------------------------------------------------------
__global__ void k_gather(const float* __restrict__ emb, const int* __restrict__ tgt,
                         float* __restrict__ Xemb)
{
    const int o = blockIdx.x * 256 + threadIdx.x;  // 131072
    const int r = o >> 7, k4 = (o & 127) * 4;
    const int b = r >> 5, t = r & 31;
    const int tok = t ? tgt[b * T_ + t - 1] : 0;
    *(float4*)(Xemb + (size_t)r * 512 + k4) = *(const float4*)(emb + (size_t)tok * 512 + k4);
}

// ---------------------------------------------------------------------------
// q partials: thread = (b, j, c) c in 0..3, chunk 128 of K=512.
// ---------------------------------------------------------------------------
__global__ void k_q(const float* __restrict__ h, const float* __restrict__ Wa_w,
                    float* __restrict__ qp)
{
    const int o = blockIdx.x * 256 + threadIdx.x;  // 65536
    const int b = o & 31, j = (o >> 5) & 511, c = o >> 14;
    const float* x = h + b * 512 + c * 128;
    const float* w = Wa_w + (size_t)j * 512 + c * 128;
    float s = 0.f;
#pragma unroll 8
    for (int k = 0; k < 128; k += 4)
        s += dot4(*(const float4*)(x + k), *(const float4*)(w + k));
    qp[c * 16384 + b * 512 + j] = s;
}

// ---------------------------------------------------------------------------
// Attention: one block per b. q = sum of 4 partials + Wa_b.
// ---------------------------------------------------------------------------
__global__ void k_attn(const float* __restrict__ qp, const float* __restrict__ Wa_b,
                       const float* __restrict__ ua, const float* __restrict__ Va_w,
                       const float* __restrict__ Va_b, const float* __restrict__ enc,
                       float* __restrict__ ctx, float* __restrict__ attn_out, int t)
{
    __shared__ float qs[512];
    __shared__ float parts[64][4];
    __shared__ float wsm[64];
    const int b = blockIdx.x;
    const int tid = threadIdx.x;

    for (int i = tid; i < 512; i += 256) {
        const int ix = b * 512 + i;
        qs[i] = qp[ix] + qp[16384 + ix] + qp[32768 + ix] + qp[49152 + ix] + Wa_b[i];
    }
    __syncthreads();

    const int s = tid >> 2, p = tid & 3;
    {
        const float* uar = ua + ((size_t)(b * 64 + s)) * 512 + p * 128;
        const float* vp = Va_w + p * 128;
        float acc = 0.f;
#pragma unroll 8
        for (int k = 0; k < 128; k += 4) {
            float4 u4 = *(const float4*)(uar + k);
            float4 v4 = *(const float4*)(vp + k);
            float4 q4 = *(const float4*)(&qs[p * 128 + k]);
            acc += v4.x * tanh_fast(q4.x + u4.x) + v4.y * tanh_fast(q4.y + u4.y)
                 + v4.z * tanh_fast(q4.z + u4.z) + v4.w * tanh_fast(q4.w + u4.w);
        }
        parts[s][p] = acc;
    }
    __syncthreads();

    if (tid < 64) {
        float sc = parts[tid][0] + parts[tid][1] + parts[tid][2] + parts[tid][3] + Va_b[0];
        float mx = sc;
        for (int off = 32; off; off >>= 1) mx = fmaxf(mx, __shfl_down(mx, off));
        mx = __shfl(mx, 0);
        float e = __expf(sc - mx);
        float sum = e;
        for (int off = 32; off; off >>= 1) sum += __shfl_down(sum, off);
        sum = __shfl(sum, 0);
        float w = e / sum;
        wsm[tid] = w;
        attn_out[((size_t)b * T_ + t) * 64 + tid] = w;
    }
    __syncthreads();

    {
        const int mm = tid * 4;
        float4 a = {0.f, 0.f, 0.f, 0.f};
        for (int s2 = 0; s2 < 64; s2++) {
            const float w = wsm[s2];
            const float4 e4 = *(const float4*)(enc + ((size_t)(b * 64 + s2)) * 1024 + mm);
            a.x += w * e4.x; a.y += w * e4.y; a.z += w * e4.z; a.w += w * e4.w;
        }
        *(float4*)(ctx + b * 1024 + mm) = a;
    }
}

// ---------------------------------------------------------------------------
// gh + gx_ctx partials, 3 gates per thread (x-load amortized).
// gh: o < 65536: (b,j,c) c 0..3, chunk 128 of K=512 over h, W_hh rows.
// gx: rest:      (b,j,c) c 0..7, chunk 128 of K=1024 over ctx, W_ih[:,512:].
// ---------------------------------------------------------------------------
__global__ void k_ggx(const float* __restrict__ h, const float* __restrict__ ctx,
                      const float* __restrict__ W_hh, const float* __restrict__ W_ih,
                      float* __restrict__ ghp, float* __restrict__ gxp)
{
    const int o = blockIdx.x * 256 + threadIdx.x;  // 196608
    if (o < 65536) {
        const int b = o & 31, j = (o >> 5) & 511, c = o >> 14;  // c 0..3
        const float* x  = h + b * 512 + c * 128;
        const float* w0 = W_hh + (size_t)j * 512 + c * 128;
        const float* w1 = w0 + 512 * 512;
        const float* w2 = w1 + 512 * 512;
        float s0 = 0.f, s1 = 0.f, s2 = 0.f;
#pragma unroll 8
        for (int k = 0; k < 128; k += 4) {
            const float4 xv = *(const float4*)(x + k);
            s0 += dot4(xv, *(const float4*)(w0 + k));
            s1 += dot4(xv, *(const float4*)(w1 + k));
            s2 += dot4(xv, *(const float4*)(w2 + k));
        }
        const int ix = b * 512 + j;
        ghp[(c * 3 + 0) * 16384 + ix] = s0;
        ghp[(c * 3 + 1) * 16384 + ix] = s1;
        ghp[(c * 3 + 2) * 16384 + ix] = s2;
    } else {
        const int oo = o - 65536;
        const int b = oo & 31, j = (oo >> 5) & 511, c = oo >> 14;  // c 0..7
        const float* x  = ctx + b * 1024 + c * 128;
        const float* w0 = W_ih + (size_t)j * 1536 + 512 + c * 128;
        const float* w1 = w0 + 512 * 1536;
        const float* w2 = w1 + 512 * 1536;
        float s0 = 0.f, s1 = 0.f, s2 = 0.f;
#pragma unroll 8
        for (int k = 0; k < 128; k += 4) {
            const float4 xv = *(const float4*)(x + k);
            s0 += dot4(xv, *(const float4*)(w0 + k));
            s1 += dot4(xv, *(const float4*)(w1 + k));
            s2 += dot4(xv, *(const float4*)(w2 + k));
        }
        const int ix = b * 512 + j;
        gxp[(c * 3 + 0) * 16384 + ix] = s0;
        gxp[(c * 3 + 1) * 16384 + ix] = s1;
        gxp[(c * 3 + 2) * 16384 + ix] = s2;
    }
}

// ---------------------------------------------------------------------------
// GRU finalize: sum partials, gates, h update. Gxe already holds emb-part+b_ih.
// ---------------------------------------------------------------------------
__global__ void k_fin(const float* __restrict__ ghp, const float* __restrict__ gxp,
                      const float* __restrict__ Gxe, const float* __restrict__ b_hh,
                      float* __restrict__ h, unsigned short* __restrict__ Hall,
                      float* __restrict__ hfin, int t)
{
    const int o = blockIdx.x * 256 + threadIdx.x;  // 16384 (o == b*512+j)
    const int b = o >> 9, j = o & 511;
    float gh0 = b_hh[j], gh1 = b_hh[512 + j], gh2 = b_hh[1024 + j];
#pragma unroll
    for (int c = 0; c < 4; c++) {
        gh0 += ghp[(c * 3 + 0) * 16384 + o];
        gh1 += ghp[(c * 3 + 1) * 16384 + o];
        gh2 += ghp[(c * 3 + 2) * 16384 + o];
    }
    const float* gxe = Gxe + ((size_t)(b * T_ + t)) * 1536;
    float gx0 = gxe[j], gx1 = gxe[512 + j], gx2 = gxe[1024 + j];
#pragma unroll
    for (int c = 0; c < 8; c++) {
        gx0 += gxp[(c * 3 + 0) * 16384 + o];
        gx1 += gxp[(c * 3 + 1) * 16384 + o];
        gx2 += gxp[(c * 3 + 2) * 16384 + o];
    }
    const float r = sigmoid_fast(gx0 + gh0);
    const float z = sigmoid_fast(gx1 + gh1);
    const float n = tanh_fast(gx2 + r * gh2);
    const float hn = (1.f - z) * n + z * h[o];
    h[o] = hn;
    Hall[((size_t)b * T_ + t) * 512 + j] = f2bf(hn);
    if (hfin) hfin[o] = hn;
}

// ---------------------------------------------------------------------------
// Online log_softmax over V=32000 per row, in place. One block per row.
// ---------------------------------------------------------------------------
__global__ void k_logsoftmax(float* __restrict__ logits)
{
    __shared__ float rm[4], rs[4];
    const int row = blockIdx.x;
    float* p = logits + (size_t)row * V_;
    const int tid = threadIdx.x;

    float m = -1e30f, s = 0.f;
    for (int i = tid * 4; i < V_; i += 1024) {
        const float4 x = *(const float4*)(p + i);
        const float m4 = fmaxf(fmaxf(x.x, x.y), fmaxf(x.z, x.w));
        const float mn = fmaxf(m, m4);
        s = s * __expf(m - mn) + __expf(x.x - mn) + __expf(x.y - mn)
          + __expf(x.z - mn) + __expf(x.w - mn);
        m = mn;
    }
    for (int off = 32; off; off >>= 1) {
        const float m2 = __shfl_down(m, off), s2 = __shfl_down(s, off);
        const float mn = fmaxf(m, m2);
        s = s * __expf(m - mn) + s2 * __expf(m2 - mn);
        m = mn;
    }
    if ((tid & 63) == 0) { rm[tid >> 6] = m; rs[tid >> 6] = s; }
    __syncthreads();
    const float M = fmaxf(fmaxf(rm[0], rm[1]), fmaxf(rm[2], rm[3]));
    const float S = rs[0] * __expf(rm[0] - M) + rs[1] * __expf(rm[1] - M)
                  + rs[2] * __expf(rm[2] - M) + rs[3] * __expf(rm[3] - M);
    const float lse = M + __logf(S);

    for (int i = tid * 4; i < V_; i += 1024) {
        float4 x = *(const float4*)(p + i);
        x.x -= lse; x.y -= lse; x.z -= lse; x.w -= lse;
        *(float4*)(p + i) = x;
    }
}

// ---------------------------------------------------------------------------
extern "C" void kernel_launch(void* const* d_in, const int* in_sizes, int n_in,
                              void* d_out, int out_size, void* d_ws, size_t ws_size,
                              hipStream_t stream)
{
    const float* enc   = (const float*)d_in[0];   // [B,S,2H]
    const float* ehid  = (const float*)d_in[1];   // [1,B,2H]
    const int*   tgt   = (const int*)d_in[2];     // [B,T]
    const float* emb   = (const float*)d_in[3];   // [V,H]
    const float* Wa_w  = (const float*)d_in[4];   // [H,H]
    const float* Wa_b  = (const float*)d_in[5];
    const float* Ua_w  = (const float*)d_in[6];   // [H,2H]
    const float* Ua_b  = (const float*)d_in[7];
    const float* Va_w  = (const float*)d_in[8];   // [1,H]
    const float* Va_b  = (const float*)d_in[9];   // [1]
    const float* W_ih  = (const float*)d_in[10];  // [3H,3H]
    const float* b_ih  = (const float*)d_in[11];
    const float* W_hh  = (const float*)d_in[12];  // [3H,H]
    const float* b_hh  = (const float*)d_in[13];
    const float* Wh    = (const float*)d_in[14];  // [H,2H]
    const float* bh    = (const float*)d_in[15];
    const float* out_w = (const float*)d_in[16];  // [V,H]
    const float* out_b = (const float*)d_in[17];  // [V]

    float* outp = (float*)d_out;
    float* lp   = outp;                 // [B,T,V] = 32,768,000 floats
    float* hf   = outp + 32768000;      // [1,B,H]
    float* attn = outp + 32784384;      // [B,T,S]

    // Transient scratch inside the lp region (dead before the logits GEMM
    // overwrites all of lp):
    float* Gxe  = lp;                   // 1,572,864  [B*T, 3H] emb-part + b_ih
    float* Xemb = lp + 1572864;         //   524,288  [B*T, H]
    float* qp   = lp + 2097152;         //    65,536  4 x [B*H]
    float* ghp  = lp + 2162688;         //   196,608  12 x [B*H]
    float* gxp  = lp + 2359296;         //   393,216  24 x [B*H]
    float* h0p  = gxp;                  // setup-only alias (4 x 16384)

    // Persistent ws (~5.4 MB)
    float* ws  = (float*)d_ws;
    float* h   = ws;                    // 16,384
    float* ctx = ws + 16384;            // 32,768
    float* ua  = ws + 49152;            // 1,048,576  [B*S, H]
    unsigned short* Hall = (unsigned short*)(ws + 1097728);  // [B*T, H] bf16

    // ---- setup ----
    k_h0part<<<256, 256, 0, stream>>>(ehid, Wh, h0p);
    k_h0fin<<<64, 256, 0, stream>>>(h0p, bh, h);
    k_gather<<<512, 256, 0, stream>>>(emb, tgt, Xemb);
    gemm_bt<false><<<dim3(16, 4), 256, 0, stream>>>(enc, Ua_w, Ua_b, ua,
                                                    2048, 512, 1024, 1024);
    gemm_bt<false><<<dim3(8, 12), 256, 0, stream>>>(Xemb, W_ih, b_ih, Gxe,
                                                    1024, 1536, 512, 1536);

    // ---- sequential scan ----
    for (int t = 0; t < T_; t++) {
        k_q<<<256, 256, 0, stream>>>(h, Wa_w, qp);
        k_attn<<<32, 256, 0, stream>>>(qp, Wa_b, ua, Va_w, Va_b, enc, ctx, attn, t);
        k_ggx<<<768, 256, 0, stream>>>(h, ctx, W_hh, W_ih, ghp, gxp);
        k_fin<<<64, 256, 0, stream>>>(ghp, gxp, Gxe, b_hh, h, Hall,
                                      (t == T_ - 1) ? hf : nullptr, t);
    }

    // ---- logits + log_softmax ----
    gemm_bt<true><<<dim3(8, 250), 256, 0, stream>>>(Hall, out_w, out_b, lp,
                                                    1024, V_, 512, 512);
    k_logsoftmax<<<1024, 256, 0, stream>>>(lp);
}